// Round 1
// baseline (131.033 us; speedup 1.0000x reference)
//
#include <hip/hip_runtime.h>
#include <math.h>

#define PCNT 2048
#define CDIM 512

// ------------------------------------------------------------------
// K1: xr = inputs @ W.T + b ; logit = softmax(xr)  -> out[row*4+c]
// wave-per-row, 4 waves/block, 16 rows per wave.
// ------------------------------------------------------------------
__global__ __launch_bounds__(256) void k_gemv_softmax(
    const float* __restrict__ in, const float* __restrict__ W,
    const float* __restrict__ bias, float* __restrict__ out)
{
    __shared__ float w_lds[4 * CDIM];
    int tid = threadIdx.x;
    for (int e = tid; e < 4 * CDIM; e += 256) w_lds[e] = W[e];
    __syncthreads();
    float b0 = bias[0], b1 = bias[1], b2 = bias[2], b3 = bias[3];
    int wave = tid >> 6, lane = tid & 63;
    int row0 = blockIdx.x * 64 + wave * 16;
    for (int r = 0; r < 16; ++r) {
        int row = row0 + r;
        const float4* ip = (const float4*)(in + (size_t)row * CDIM);
        float a0 = 0.f, a1 = 0.f, a2 = 0.f, a3 = 0.f;
#pragma unroll
        for (int k = 0; k < 2; ++k) {
            int idx = lane + k * 64;
            float4 v = ip[idx];
            int e = idx * 4;
            a0 += v.x * w_lds[0*CDIM+e] + v.y * w_lds[0*CDIM+e+1] + v.z * w_lds[0*CDIM+e+2] + v.w * w_lds[0*CDIM+e+3];
            a1 += v.x * w_lds[1*CDIM+e] + v.y * w_lds[1*CDIM+e+1] + v.z * w_lds[1*CDIM+e+2] + v.w * w_lds[1*CDIM+e+3];
            a2 += v.x * w_lds[2*CDIM+e] + v.y * w_lds[2*CDIM+e+1] + v.z * w_lds[2*CDIM+e+2] + v.w * w_lds[2*CDIM+e+3];
            a3 += v.x * w_lds[3*CDIM+e] + v.y * w_lds[3*CDIM+e+1] + v.z * w_lds[3*CDIM+e+2] + v.w * w_lds[3*CDIM+e+3];
        }
#pragma unroll
        for (int off = 32; off > 0; off >>= 1) {
            a0 += __shfl_down(a0, off, 64);
            a1 += __shfl_down(a1, off, 64);
            a2 += __shfl_down(a2, off, 64);
            a3 += __shfl_down(a3, off, 64);
        }
        if (lane == 0) {
            a0 += b0; a1 += b1; a2 += b2; a3 += b3;
            float m = fmaxf(fmaxf(a0, a1), fmaxf(a2, a3));
            float e0 = expf(a0 - m), e1 = expf(a1 - m), e2 = expf(a2 - m), e3 = expf(a3 - m);
            float inv = 1.f / (e0 + e1 + e2 + e3);
            ((float4*)out)[row] = make_float4(e0 * inv, e1 * inv, e2 * inv, e3 * inv);
        }
    }
}

// ------------------------------------------------------------------
// K2: seeds. One block per batch b. For c in 0..2: cnt = #(sc>0.5),
// amax = first argmax. seed bit = (cnt<=1) ? (j==amax) : (sc>0.5)
// ------------------------------------------------------------------
__global__ __launch_bounds__(256) void k_seeds(
    const float* __restrict__ ps, unsigned char* __restrict__ seedpack)
{
    int b = blockIdx.x;
    int tid = threadIdx.x;
    __shared__ float sval[256];
    __shared__ int   sidx[256];
    __shared__ int   scnt[256];
    unsigned char packs[PCNT / 256];
#pragma unroll
    for (int t = 0; t < PCNT / 256; ++t) packs[t] = 0;

    for (int c = 0; c < 3; ++c) {
        float bestv = -1e30f; int besti = 0; int cnt = 0;
#pragma unroll
        for (int t = 0; t < PCNT / 256; ++t) {
            int j = tid + t * 256;
            float v = ps[((size_t)b * PCNT + j) * 4 + c];
            if (v > 0.5f) cnt++;
            if (v > bestv) { bestv = v; besti = j; }   // ascending j -> first max kept
        }
        sval[tid] = bestv; sidx[tid] = besti; scnt[tid] = cnt;
        __syncthreads();
        for (int s = 128; s > 0; s >>= 1) {
            if (tid < s) {
                float v2 = sval[tid + s]; int i2 = sidx[tid + s];
                if (v2 > sval[tid] || (v2 == sval[tid] && i2 < sidx[tid])) { sval[tid] = v2; sidx[tid] = i2; }
                scnt[tid] += scnt[tid + s];
            }
            __syncthreads();
        }
        int totcnt = scnt[0];
        int amax   = sidx[0];
        __syncthreads();   // everyone has read [0] before next class overwrites
#pragma unroll
        for (int t = 0; t < PCNT / 256; ++t) {
            int j = tid + t * 256;
            float v = ps[((size_t)b * PCNT + j) * 4 + c];
            bool bit = (totcnt <= 1) ? (j == amax) : (v > 0.5f);
            if (bit) packs[t] |= (unsigned char)(1 << c);
        }
    }
#pragma unroll
    for (int t = 0; t < PCNT / 256; ++t)
        seedpack[(size_t)b * PCNT + tid + t * 256] = packs[t];
}

// ------------------------------------------------------------------
// K3: assignment. Block = (b, 64-row i-tile). 4 lanes share one i,
// each scanning a 512-wide j quarter; exact (max, min-j) shfl merge.
// ------------------------------------------------------------------
__global__ __launch_bounds__(256) void k_assign(
    const float* __restrict__ rois, const float* __restrict__ ps,
    const float* __restrict__ labels, const unsigned char* __restrict__ seedpack,
    int* __restrict__ cls_out, float* __restrict__ wrow_out, int* __restrict__ imb)
{
    __shared__ float4 lrois[PCNT];        // 32 KB
    __shared__ float  larea[PCNT];        // 8 KB
    __shared__ unsigned char lseed[PCNT]; // 2 KB
    __shared__ int hist[4];

    int b    = blockIdx.x >> 5;   // 32 tiles per batch
    int tile = blockIdx.x & 31;
    int tid  = threadIdx.x;
    if (tid < 4) hist[tid] = 0;

    const float4* rb = (const float4*)(rois + (size_t)b * PCNT * 4);
    for (int j = tid; j < PCNT; j += 256) {
        float4 q = rb[j];
        lrois[j] = q;
        larea[j] = (q.z - q.x) * (q.w - q.y);
        lseed[j] = seedpack[(size_t)b * PCNT + j];
    }
    __syncthreads();

    int i  = tile * 64 + (tid >> 2);
    int jq = tid & 3;
    float4 r = lrois[i];
    float areaA = larea[i];

    float best0 = -1.f, best1 = -1.f, best2 = -1.f;
    int   bj0 = PCNT, bj1 = PCNT, bj2 = PCNT;
    int jbase = jq * (PCNT / 4);
    for (int jj = 0; jj < PCNT / 4; ++jj) {
        int j = jbase + jj;
        unsigned char sp = lseed[j];
        float4 q = lrois[j];
        float lx = fmaxf(r.x, q.x), ly = fmaxf(r.y, q.y);
        float rx = fminf(r.z, q.z), ry = fminf(r.w, q.w);
        float ww = fmaxf(rx - lx, 0.f);
        float hh = fmaxf(ry - ly, 0.f);
        float inter = ww * hh;
        float iou = inter / (areaA + larea[j] - inter);
        if ((sp & 1) && iou > best0) { best0 = iou; bj0 = j; }
        if ((sp & 2) && iou > best1) { best1 = iou; bj1 = j; }
        if ((sp & 4) && iou > best2) { best2 = iou; bj2 = j; }
    }
    // exact merge across the 4 j-quarters (max value, min index on ties)
#pragma unroll
    for (int off = 1; off < 4; off <<= 1) {
        float v; int j2;
        v = __shfl_xor(best0, off, 64); j2 = __shfl_xor(bj0, off, 64);
        if (v > best0 || (v == best0 && j2 < bj0)) { best0 = v; bj0 = j2; }
        v = __shfl_xor(best1, off, 64); j2 = __shfl_xor(bj1, off, 64);
        if (v > best1 || (v == best1 && j2 < bj1)) { best1 = v; bj1 = j2; }
        v = __shfl_xor(best2, off, 64); j2 = __shfl_xor(bj2, off, 64);
        if (v > best2 || (v == best2 && j2 < bj2)) { best2 = v; bj2 = j2; }
    }

    if (jq == 0) {
        bj0 = (bj0 < PCNT) ? bj0 : 0;
        bj1 = (bj1 < PCNT) ? bj1 : 0;
        bj2 = (bj2 < PCNT) ? bj2 : 0;
        float lab0 = labels[b * 4 + 0];
        float lab1 = labels[b * 4 + 1];
        float lab2 = labels[b * 4 + 2];
        float x0 = ps[((size_t)b * PCNT + bj0) * 4 + 0];
        float x1 = ps[((size_t)b * PCNT + bj1) * 4 + 1];
        float x2 = ps[((size_t)b * PCNT + bj2) * 4 + 2];
        float I = -1.f; int cls = 3; float wv = 1.f;
        if (lab0 > 0.f && best0 >= 0.5f && best0 > I) { I = best0; wv = x0; cls = 0; }
        if (lab1 > 0.f && best1 >= 0.5f && best1 > I) { I = best1; wv = x1; cls = 1; }
        if (lab2 > 0.f && best2 >= 0.5f && best2 > I) { I = best2; wv = x2; cls = 2; }
        int row = b * PCNT + i;
        cls_out[row]  = cls;
        wrow_out[row] = wv;
        atomicAdd(&hist[cls], 1);
    }
    __syncthreads();
    if (tid < 4 && hist[tid] > 0) atomicAdd(&imb[tid], hist[tid]);
}

// ------------------------------------------------------------------
// K4/K5: deterministic loss reduction
// ------------------------------------------------------------------
__global__ __launch_bounds__(256) void k_loss_partial(
    const float* __restrict__ logit, const float* __restrict__ labels,
    const int* __restrict__ cls, const float* __restrict__ wrow,
    const int* __restrict__ imb, float* __restrict__ partials, int rows)
{
    __shared__ float simb[4];
    __shared__ float sred[256];
    int tid = threadIdx.x;
    if (tid < 4) simb[tid] = (float)imb[tid] + 1e-7f;
    __syncthreads();
    float sum = 0.f;
    for (int row = blockIdx.x * 256 + tid; row < rows; row += gridDim.x * 256) {
        int k = cls[row];
        float w = wrow[row];
        int b = row >> 11;           // P = 2048
        float l = logit[row * 4 + k];
        float p = fminf(fmaxf(l, 1e-7f), 1.f - 1e-7f);
        float om = 1.f - p;
        float fl = -logf(p) * om * om;
        float lab = (k == 3) ? 1.f : labels[b * 4 + k];
        float wu = 10.f * expf(l) * (1.f - lab) + lab;
        sum += w * fl / simb[k] * wu;
    }
    sred[tid] = sum;
    __syncthreads();
    for (int s = 128; s > 0; s >>= 1) {
        if (tid < s) sred[tid] += sred[tid + s];
        __syncthreads();
    }
    if (tid == 0) partials[blockIdx.x] = sred[0];
}

__global__ __launch_bounds__(128) void k_loss_final(
    const float* __restrict__ partials, float* __restrict__ out_loss,
    int nblk, float invB)
{
    __shared__ float sred[128];
    int tid = threadIdx.x;
    sred[tid] = (tid < nblk) ? partials[tid] : 0.f;
    __syncthreads();
    for (int s = 64; s > 0; s >>= 1) {
        if (tid < s) sred[tid] += sred[tid + s];
        __syncthreads();
    }
    if (tid == 0) *out_loss = sred[0] * invB;
}

extern "C" void kernel_launch(void* const* d_in, const int* in_sizes, int n_in,
                              void* d_out, int out_size, void* d_ws, size_t ws_size,
                              hipStream_t stream)
{
    const float* inputs = (const float*)d_in[0];
    const float* ps     = (const float*)d_in[1];
    const float* labels = (const float*)d_in[2];
    const float* rois   = (const float*)d_in[3];
    const float* fcw    = (const float*)d_in[4];
    const float* fcb    = (const float*)d_in[5];

    int B = in_sizes[2] / 4;            // 16
    int P = in_sizes[1] / (4 * B);      // 2048
    int rows = B * P;                   // 32768
    float* out = (float*)d_out;

    char* ws = (char*)d_ws;
    int*   imb      = (int*)ws;                              // 16 B
    float* partials = (float*)(ws + 256);                    // 512 B
    unsigned char* seedpack = (unsigned char*)(ws + 1024);   // rows B
    int*   cls  = (int*)(ws + 1024 + rows);                  // rows*4 B
    float* wrow = (float*)(ws + 1024 + rows + (size_t)rows * 4);

    hipMemsetAsync(imb, 0, 16, stream);
    k_gemv_softmax<<<rows / 64, 256, 0, stream>>>(inputs, fcw, fcb, out);
    k_seeds<<<B, 256, 0, stream>>>(ps, seedpack);
    k_assign<<<B * (P / 64), 256, 0, stream>>>(rois, ps, labels, seedpack, cls, wrow, imb);
    const int NBLK = 128;
    k_loss_partial<<<NBLK, 256, 0, stream>>>(out, labels, cls, wrow, imb, partials, rows);
    k_loss_final<<<1, 128, 0, stream>>>(partials, out + (size_t)rows * 4, NBLK, 1.f / (float)B);
}

// Round 2
// 93.094 us; speedup vs baseline: 1.4075x; 1.4075x over previous
//
#include <hip/hip_runtime.h>
#include <math.h>

#define PCNT 2048
#define CDIM 512

// ------------------------------------------------------------------
// K1: xr = inputs @ W.T + b ; logit = softmax(xr)  -> out[row*4+c]
// wave-per-row-group, 4 waves/block, 16 rows per wave.
// ------------------------------------------------------------------
__global__ __launch_bounds__(256) void k_gemv_softmax(
    const float* __restrict__ in, const float* __restrict__ W,
    const float* __restrict__ bias, float* __restrict__ out)
{
    __shared__ float w_lds[4 * CDIM];
    int tid = threadIdx.x;
    for (int e = tid; e < 4 * CDIM; e += 256) w_lds[e] = W[e];
    __syncthreads();
    float b0 = bias[0], b1 = bias[1], b2 = bias[2], b3 = bias[3];
    int wave = tid >> 6, lane = tid & 63;
    int row0 = blockIdx.x * 64 + wave * 16;
    for (int r = 0; r < 16; ++r) {
        int row = row0 + r;
        const float4* ip = (const float4*)(in + (size_t)row * CDIM);
        float a0 = 0.f, a1 = 0.f, a2 = 0.f, a3 = 0.f;
#pragma unroll
        for (int k = 0; k < 2; ++k) {
            int idx = lane + k * 64;
            float4 v = ip[idx];
            int e = idx * 4;
            a0 += v.x * w_lds[0*CDIM+e] + v.y * w_lds[0*CDIM+e+1] + v.z * w_lds[0*CDIM+e+2] + v.w * w_lds[0*CDIM+e+3];
            a1 += v.x * w_lds[1*CDIM+e] + v.y * w_lds[1*CDIM+e+1] + v.z * w_lds[1*CDIM+e+2] + v.w * w_lds[1*CDIM+e+3];
            a2 += v.x * w_lds[2*CDIM+e] + v.y * w_lds[2*CDIM+e+1] + v.z * w_lds[2*CDIM+e+2] + v.w * w_lds[2*CDIM+e+3];
            a3 += v.x * w_lds[3*CDIM+e] + v.y * w_lds[3*CDIM+e+1] + v.z * w_lds[3*CDIM+e+2] + v.w * w_lds[3*CDIM+e+3];
        }
#pragma unroll
        for (int off = 32; off > 0; off >>= 1) {
            a0 += __shfl_down(a0, off, 64);
            a1 += __shfl_down(a1, off, 64);
            a2 += __shfl_down(a2, off, 64);
            a3 += __shfl_down(a3, off, 64);
        }
        if (lane == 0) {
            a0 += b0; a1 += b1; a2 += b2; a3 += b3;
            float m = fmaxf(fmaxf(a0, a1), fmaxf(a2, a3));
            float e0 = expf(a0 - m), e1 = expf(a1 - m), e2 = expf(a2 - m), e3 = expf(a3 - m);
            float inv = 1.f / (e0 + e1 + e2 + e3);
            ((float4*)out)[row] = make_float4(e0 * inv, e1 * inv, e2 * inv, e3 * inv);
        }
    }
}

// ------------------------------------------------------------------
// K2: seeds. One block per (b,c). Writes per-class seed plane (0/1).
// seed = (cnt<=1) ? (j==first_argmax) : (sc>0.5)
// ------------------------------------------------------------------
__global__ __launch_bounds__(256) void k_seeds(
    const float* __restrict__ ps, unsigned char* __restrict__ planes, int B)
{
    int b = blockIdx.x / 3, c = blockIdx.x % 3;
    int tid = threadIdx.x;
    __shared__ float sval[256];
    __shared__ int   sidx[256];
    __shared__ int   scnt[256];

    float bestv = -1e30f; int besti = 0; int cnt = 0;
#pragma unroll
    for (int t = 0; t < PCNT / 256; ++t) {
        int j = tid + t * 256;
        float v = ps[((size_t)b * PCNT + j) * 4 + c];
        if (v > 0.5f) cnt++;
        if (v > bestv) { bestv = v; besti = j; }   // ascending j -> first max kept
    }
    sval[tid] = bestv; sidx[tid] = besti; scnt[tid] = cnt;
    __syncthreads();
    for (int s = 128; s > 0; s >>= 1) {
        if (tid < s) {
            float v2 = sval[tid + s]; int i2 = sidx[tid + s];
            if (v2 > sval[tid] || (v2 == sval[tid] && i2 < sidx[tid])) { sval[tid] = v2; sidx[tid] = i2; }
            scnt[tid] += scnt[tid + s];
        }
        __syncthreads();
    }
    int totcnt = scnt[0];
    int amax   = sidx[0];
    unsigned char* pl = planes + ((size_t)c * B + b) * PCNT;
#pragma unroll
    for (int t = 0; t < PCNT / 256; ++t) {
        int j = tid + t * 256;
        float v = ps[((size_t)b * PCNT + j) * 4 + c];
        bool bit = (totcnt <= 1) ? (j == amax) : (v > 0.5f);
        pl[j] = bit ? 1 : 0;
    }
}

// ------------------------------------------------------------------
// K3: assignment. Block = (b, 64-row i-tile), 512 threads.
// 8 lanes share one i; j interleaved (j = jj*8 + jq) -> conflict-free
// b128 LDS reads. Two j-phases of 1024 to stay under 64KB LDS.
// ------------------------------------------------------------------
__global__ __launch_bounds__(512, 4) void k_assign(
    const float* __restrict__ rois, const float* __restrict__ ps,
    const float* __restrict__ labels, const unsigned char* __restrict__ planes,
    int* __restrict__ cls_out, float* __restrict__ wrow_out, int* __restrict__ imb,
    int B)
{
    __shared__ float4 lrois[1024];   // 16 KB
    __shared__ float4 lmeta[1024];   // 16 KB  (area, m0, m1, m2)
    __shared__ int hist[4];

    int b    = blockIdx.x >> 5;   // 32 tiles per batch
    int tile = blockIdx.x & 31;
    int tid  = threadIdx.x;
    if (tid < 4) hist[tid] = 0;

    const float4* rb = (const float4*)(rois + (size_t)b * PCNT * 4);
    const unsigned char* pl0 = planes + (size_t)b * PCNT;
    const unsigned char* pl1 = planes + ((size_t)B + b) * PCNT;
    const unsigned char* pl2 = planes + ((size_t)2 * B + b) * PCNT;

    int i  = tile * 64 + (tid >> 3);
    int jq = tid & 7;
    float4 r = rb[i];
    float areaA = (r.z - r.x) * (r.w - r.y);

    float best0 = -1.f, best1 = -1.f, best2 = -1.f;
    int   bj0 = 0, bj1 = 0, bj2 = 0;

    for (int ph = 0; ph < 2; ++ph) {
        __syncthreads();
        for (int jl = tid; jl < 1024; jl += 512) {
            int j = ph * 1024 + jl;
            float4 q = rb[j];
            lrois[jl] = q;
            lmeta[jl] = make_float4((q.z - q.x) * (q.w - q.y),
                                    (float)pl0[j], (float)pl1[j], (float)pl2[j]);
        }
        __syncthreads();
#pragma unroll 4
        for (int jj = 0; jj < 128; ++jj) {
            int jl = jj * 8 + jq;
            float4 q = lrois[jl];
            float4 m = lmeta[jl];
            float lx = fmaxf(r.x, q.x), ly = fmaxf(r.y, q.y);
            float rx = fminf(r.z, q.z), ry = fminf(r.w, q.w);
            float ww = fmaxf(rx - lx, 0.f);
            float hh = fmaxf(ry - ly, 0.f);
            float inter = ww * hh;
            float u = (areaA + m.x) - inter;
            float ioup1 = fmaf(inter, __builtin_amdgcn_rcpf(u), 1.0f); // iou + 1
            int j = ph * 1024 + jl;
            float t0 = fmaf(ioup1, m.y, -1.0f);   // seed? iou : -1
            if (t0 > best0) { best0 = t0; bj0 = j; }
            float t1 = fmaf(ioup1, m.z, -1.0f);
            if (t1 > best1) { best1 = t1; bj1 = j; }
            float t2 = fmaf(ioup1, m.w, -1.0f);
            if (t2 > best2) { best2 = t2; bj2 = j; }
        }
    }

    // exact merge across the 8 j-lanes (max value, min index on ties)
#pragma unroll
    for (int off = 1; off < 8; off <<= 1) {
        float v; int j2;
        v = __shfl_xor(best0, off, 64); j2 = __shfl_xor(bj0, off, 64);
        if (v > best0 || (v == best0 && j2 < bj0)) { best0 = v; bj0 = j2; }
        v = __shfl_xor(best1, off, 64); j2 = __shfl_xor(bj1, off, 64);
        if (v > best1 || (v == best1 && j2 < bj1)) { best1 = v; bj1 = j2; }
        v = __shfl_xor(best2, off, 64); j2 = __shfl_xor(bj2, off, 64);
        if (v > best2 || (v == best2 && j2 < bj2)) { best2 = v; bj2 = j2; }
    }

    if (jq == 0) {
        float lab0 = labels[b * 4 + 0];
        float lab1 = labels[b * 4 + 1];
        float lab2 = labels[b * 4 + 2];
        float x0 = ps[((size_t)b * PCNT + bj0) * 4 + 0];
        float x1 = ps[((size_t)b * PCNT + bj1) * 4 + 1];
        float x2 = ps[((size_t)b * PCNT + bj2) * 4 + 2];
        float I = -1.f; int cls = 3; float wv = 1.f;
        if (lab0 > 0.f && best0 >= 0.5f && best0 > I) { I = best0; wv = x0; cls = 0; }
        if (lab1 > 0.f && best1 >= 0.5f && best1 > I) { I = best1; wv = x1; cls = 1; }
        if (lab2 > 0.f && best2 >= 0.5f && best2 > I) { I = best2; wv = x2; cls = 2; }
        int row = b * PCNT + i;
        cls_out[row]  = cls;
        wrow_out[row] = wv;
        atomicAdd(&hist[cls], 1);
    }
    __syncthreads();
    if (tid < 4 && hist[tid] > 0) atomicAdd(&imb[tid], hist[tid]);
}

// ------------------------------------------------------------------
// K4/K5: deterministic loss reduction
// ------------------------------------------------------------------
__global__ __launch_bounds__(256) void k_loss_partial(
    const float* __restrict__ logit, const float* __restrict__ labels,
    const int* __restrict__ cls, const float* __restrict__ wrow,
    const int* __restrict__ imb, float* __restrict__ partials, int rows)
{
    __shared__ float simb[4];
    __shared__ float sred[256];
    int tid = threadIdx.x;
    if (tid < 4) simb[tid] = (float)imb[tid] + 1e-7f;
    __syncthreads();
    float sum = 0.f;
    for (int row = blockIdx.x * 256 + tid; row < rows; row += gridDim.x * 256) {
        int k = cls[row];
        float w = wrow[row];
        int b = row >> 11;           // P = 2048
        float l = logit[row * 4 + k];
        float p = fminf(fmaxf(l, 1e-7f), 1.f - 1e-7f);
        float om = 1.f - p;
        float fl = -logf(p) * om * om;
        float lab = (k == 3) ? 1.f : labels[b * 4 + k];
        float wu = 10.f * expf(l) * (1.f - lab) + lab;
        sum += w * fl / simb[k] * wu;
    }
    sred[tid] = sum;
    __syncthreads();
    for (int s = 128; s > 0; s >>= 1) {
        if (tid < s) sred[tid] += sred[tid + s];
        __syncthreads();
    }
    if (tid == 0) partials[blockIdx.x] = sred[0];
}

__global__ __launch_bounds__(128) void k_loss_final(
    const float* __restrict__ partials, float* __restrict__ out_loss,
    int nblk, float invB)
{
    __shared__ float sred[128];
    int tid = threadIdx.x;
    sred[tid] = (tid < nblk) ? partials[tid] : 0.f;
    __syncthreads();
    for (int s = 64; s > 0; s >>= 1) {
        if (tid < s) sred[tid] += sred[tid + s];
        __syncthreads();
    }
    if (tid == 0) *out_loss = sred[0] * invB;
}

extern "C" void kernel_launch(void* const* d_in, const int* in_sizes, int n_in,
                              void* d_out, int out_size, void* d_ws, size_t ws_size,
                              hipStream_t stream)
{
    const float* inputs = (const float*)d_in[0];
    const float* ps     = (const float*)d_in[1];
    const float* labels = (const float*)d_in[2];
    const float* rois   = (const float*)d_in[3];
    const float* fcw    = (const float*)d_in[4];
    const float* fcb    = (const float*)d_in[5];

    int B = in_sizes[2] / 4;            // 16
    int P = in_sizes[1] / (4 * B);      // 2048
    int rows = B * P;                   // 32768
    float* out = (float*)d_out;

    char* ws = (char*)d_ws;
    int*   imb      = (int*)ws;                               // 16 B
    float* partials = (float*)(ws + 256);                     // 512 B
    unsigned char* planes = (unsigned char*)(ws + 1024);      // 3*rows B
    size_t off = 1024 + (size_t)3 * rows;
    off = (off + 255) & ~(size_t)255;
    int*   cls  = (int*)(ws + off);                           // rows*4 B
    float* wrow = (float*)(ws + off + (size_t)rows * 4);      // rows*4 B

    hipMemsetAsync(imb, 0, 16, stream);
    k_gemv_softmax<<<rows / 64, 256, 0, stream>>>(inputs, fcw, fcb, out);
    k_seeds<<<B * 3, 256, 0, stream>>>(ps, planes, B);
    k_assign<<<B * (P / 64), 512, 0, stream>>>(rois, ps, labels, planes, cls, wrow, imb, B);
    const int NBLK = 128;
    k_loss_partial<<<NBLK, 256, 0, stream>>>(out, labels, cls, wrow, imb, partials, rows);
    k_loss_final<<<1, 128, 0, stream>>>(partials, out + (size_t)rows * 4, NBLK, 1.f / (float)B);
}